// Round 17
// baseline (104.048 us; speedup 1.0000x reference)
//
#include <hip/hip_runtime.h>
#include <hip/hip_fp16.h>

#define BB 16
#define C 192
#define COUT 384
#define H 64
#define W 64
#define HW (H * W)
#define KK 9
#define OFFC 18
#define WROWS 18  // sample_dw staged window rows: [h0-7, h0+11)

typedef __attribute__((ext_vector_type(8))) short short8;
typedef __attribute__((ext_vector_type(8))) _Float16 half8;
typedef __attribute__((ext_vector_type(4))) float f32x4;

// round-to-nearest-even f32 -> bf16 bits
static __device__ inline unsigned short f2bf(float f) {
  union { float f; unsigned u; } v;
  v.f = f;
  unsigned r = v.u + 0x7FFF + ((v.u >> 16) & 1);
  return (unsigned short)(r >> 16);
}

union H2U { __half2 h; unsigned u; };

static __device__ inline __half2 bc_h2(unsigned u) {
  H2U v; v.u = u; return v.h;
}
static __device__ inline unsigned h2_bits(__half2 h) {
  H2U v; v.h = h; return v.u;
}

static __device__ inline half8 ld_frag8h(const unsigned* p) {
  union { unsigned u[4]; half8 s; } v;
  uint2 a = *(const uint2*)p;
  uint2 b = *(const uint2*)(p + 2);
  v.u[0] = a.x; v.u[1] = a.y; v.u[2] = b.x; v.u[3] = b.y;
  return v.s;
}

// ---------------------------------------------------------------------------
// Merged prep: wA (bf16, offset conv) + wPW (f16 c-pairs) + wdh (f16 dw pairs)
// ---------------------------------------------------------------------------
__global__ __launch_bounds__(256) void prep_weights(
    const float* __restrict__ w_off, const float* __restrict__ w_pw,
    const float* __restrict__ w_dw, unsigned short* __restrict__ wA,
    unsigned* __restrict__ wPW, unsigned* __restrict__ wdh) {
  int idx = blockIdx.x * 256 + threadIdx.x;
  if (idx < 9 * 32 * C) {
    int k = idx / (32 * C);
    int rem = idx % (32 * C);
    int o = rem / C;
    int c = rem % C;
    float v = (o < OFFC) ? w_off[((size_t)o * C + c) * KK + k] : 0.f;
    wA[idx] = f2bf(v);
    return;
  }
  int i2 = idx - 9 * 32 * C;
  if (i2 < COUT * (C / 2)) {
    float2 v = *(const float2*)(w_pw + (size_t)i2 * 2);
    wPW[i2] = h2_bits(__floats2half2_rn(v.x, v.y));
    return;
  }
  int i3 = i2 - COUT * (C / 2);
  if (i3 < (C / 2) * KK) {
    int cp = i3 / KK;
    int k = i3 % KK;
    wdh[i3] = h2_bits(
        __floats2half2_rn(w_dw[(size_t)(2 * cp) * KK + k],
                          w_dw[(size_t)(2 * cp + 1) * KK + k]));
  }
}

// ---------------------------------------------------------------------------
// Kernel A: offset conv via bf16 MFMA [unchanged from round 16].
// 3-way K-split, 2 chunks/block with LDS restage; 4-row stripes.
// grid = B*16 rowtiles*3 = 768 blocks, 512 thr. Plain stores to part[ks].
// ---------------------------------------------------------------------------
__global__ __launch_bounds__(512) void offset_mfma(
    const float* __restrict__ x, const unsigned short* __restrict__ wA,
    float* __restrict__ part) {
  int blk = blockIdx.x;
  int ks = blk % 3;
  int rowtile = (blk / 3) & 15;
  int b = blk / 48;
  int h0 = rowtile * 4;
  int tid = threadIdx.x;
  int lane = tid & 63;
  int wv = tid >> 6;    // 0..7
  int rw = wv >> 1;     // output row offset 0..3
  int nh = wv & 1;      // col half (2 n-tiles each)
  int lpx = lane & 15;
  int lkg = lane >> 4;

  __shared__ __align__(16) unsigned short wlds[9 * 32 * 40];  // 23040 B
  __shared__ __align__(16) unsigned short xlds[6 * 68 * 40];  // 32640 B

  for (int i = tid; i < 6 * 2 * 16; i += 512) {
    int rr = i >> 5;
    int side = (i >> 4) & 1;
    int cd = i & 15;
    int m = side ? 65 : 0;
    ((unsigned*)xlds)[(rr * 68 + m) * 20 + cd] = 0u;
  }

  f32x4 acc[2][2];
#pragma unroll
  for (int t = 0; t < 2; ++t)
#pragma unroll
    for (int m = 0; m < 2; ++m) acc[t][m] = (f32x4){0.f, 0.f, 0.f, 0.f};

  const float* xb = x + (size_t)b * C * HW;

  for (int ch2 = 0; ch2 < 2; ++ch2) {
    int c0 = (ks * 2 + ch2) * 32;
    __syncthreads();

    for (int t = 0; t < 3; ++t) {
      int i = t * 512 + tid;
      if (i < 1152) {
        int ko = i >> 2;
        int cq = i & 3;
        const unsigned* src = (const unsigned*)wA + ko * 96 + (c0 >> 1) + cq * 4;
        uint2 a = *(const uint2*)src;
        uint2 bq = *(const uint2*)(src + 2);
        unsigned* dst = (unsigned*)wlds + ko * 20 + cq * 4;
        dst[0] = a.x; dst[1] = a.y; dst[2] = bq.x; dst[3] = bq.y;
      }
    }

#pragma unroll
    for (int t = 0; t < 3; ++t) {
      int i = t * 512 + tid;
      int cc2 = i / 96;
      int rem = i % 96;
      int rr = rem >> 4;
      int col0 = (rem & 15) * 4;
      int ly = h0 + rr - 1;
      unsigned d0 = 0, d1 = 0, d2 = 0, d3 = 0;
      if (ly >= 0 && ly < H) {
        const float* xp = xb + (size_t)(c0 + 2 * cc2) * HW + ly * W + col0;
        float4 a = *(const float4*)xp;
        float4 bq = *(const float4*)(xp + HW);
        d0 = ((unsigned)f2bf(bq.x) << 16) | (unsigned)f2bf(a.x);
        d1 = ((unsigned)f2bf(bq.y) << 16) | (unsigned)f2bf(a.y);
        d2 = ((unsigned)f2bf(bq.z) << 16) | (unsigned)f2bf(a.z);
        d3 = ((unsigned)f2bf(bq.w) << 16) | (unsigned)f2bf(a.w);
      }
      unsigned* xd = (unsigned*)xlds;
      int base = (rr * 68 + col0 + 1) * 20 + cc2;
      xd[base] = d0;
      xd[base + 20] = d1;
      xd[base + 40] = d2;
      xd[base + 60] = d3;
    }
    __syncthreads();

#pragma unroll
    for (int k = 0; k < 9; ++k) {
      int ki = k / 3, kj = k % 3;
      short8 af0 = *(const short8*)&wlds[(k * 32 + lpx) * 40 + lkg * 8];
      short8 af1 = *(const short8*)&wlds[(k * 32 + 16 + lpx) * 40 + lkg * 8];
#pragma unroll
      for (int t = 0; t < 2; ++t) {
        int nt = nh * 2 + t;
        short8 bf =
            *(const short8*)&xlds[((rw + ki) * 68 + nt * 16 + lpx + kj) * 40 +
                                  lkg * 8];
        acc[t][0] = __builtin_amdgcn_mfma_f32_16x16x32_bf16(af0, bf,
                                                            acc[t][0], 0, 0, 0);
        acc[t][1] = __builtin_amdgcn_mfma_f32_16x16x32_bf16(af1, bf,
                                                            acc[t][1], 0, 0, 0);
      }
    }
  }

  int h = h0 + rw;
  float* pb = part + ((size_t)ks * BB + b) * OFFC * HW + (size_t)h * W;
#pragma unroll
  for (int t = 0; t < 2; ++t) {
    int col = (nh * 2 + t) * 16 + lpx;
#pragma unroll
    for (int j = 0; j < 4; ++j) {
      int o = lkg * 4 + j;
      pb[(size_t)o * HW + col] = acc[t][0][j];
    }
    if (lkg == 0) {
#pragma unroll
      for (int j = 0; j < 2; ++j) {
        pb[(size_t)(16 + j) * HW + col] = acc[t][1][j];
      }
    }
  }
}

// ---------------------------------------------------------------------------
// Kernel B: bilinear sample + depthwise -> dwp[B][96][HW] packed f16 c-pairs.
// FUSED offset reduction: tap setup reads the 3 K-split partials + bias
// directly (no standalone reduce kernel, no offs buffer).
// csplit 4 (48 ch = 12 quads/block): grid = B*16 rowtiles*4 = 1024, 256 thr.
// ---------------------------------------------------------------------------
__global__ __launch_bounds__(256) void sample_dw(
    const float* __restrict__ x, const float* __restrict__ part,
    const float* __restrict__ b_off, const unsigned* __restrict__ wdh,
    unsigned* __restrict__ dwp) {
  int blk = blockIdx.x;
  int csplit = blk & 3;
  int rowtile = (blk >> 2) & 15;
  int b = blk >> 6;
  int tid = threadIdx.x;
  int r = tid >> 6;
  int w = tid & 63;
  int h0 = rowtile * 4;
  int h = h0 + r;
  int lo = h0 - 7;  // window rows [lo, lo+WROWS)

  __shared__ uint2 S[WROWS * 68];  // 9792 B

  for (int i = tid; i < WROWS * 4; i += 256) {
    int rr = i >> 2;
    int p = i & 3;
    int m = (p == 0) ? 0 : 64 + p;
    S[rr * 68 + m] = make_uint2(0u, 0u);
  }

  // per-pixel tap setup: offset = sum of 3 partials + bias
  const size_t PST = (size_t)BB * OFFC * HW;
  const float* pb = part + (size_t)b * OFFC * HW + (size_t)h * W + w;
  int idxAB[KK];
  __half2 w01[KK], w23[KK];
  int okmask = 0;
#pragma unroll
  for (int k = 0; k < KK; ++k) {
    int ki = k / 3, kj = k % 3;
    size_t oyi = (size_t)(2 * k) * HW;
    size_t oxi = (size_t)(2 * k + 1) * HW;
    float oy = pb[oyi] + pb[oyi + PST] + pb[oyi + 2 * PST] + b_off[2 * k];
    float ox = pb[oxi] + pb[oxi + PST] + pb[oxi + 2 * PST] + b_off[2 * k + 1];
    float py = (float)(h - 1 + ki) + oy;
    float px = (float)(w - 1 + kj) + ox;
    float y0f = floorf(py), x0f = floorf(px);
    float dy = py - y0f, dx = px - x0f;
    int y0 = (int)y0f, x0 = (int)x0f;
    int y1 = y0 + 1, x1 = x0 + 1;
    float vy0 = (y0 >= 0 && y0 < H) ? 1.f : 0.f;
    float vy1 = (y1 >= 0 && y1 < H) ? 1.f : 0.f;
    float vx0 = (x0 >= 0 && x0 < W) ? 1.f : 0.f;
    float vx1 = (x1 >= 0 && x1 < W) ? 1.f : 0.f;
    int y0c = min(max(y0, 0), H - 1);
    int y1c = min(max(y1, 0), H - 1);
    int xm = min(max(x0, -1), 65) + 1;  // plane cols (xm, xm+1)
    int wy0 = y0c - lo, wy1 = y1c - lo;
    bool ok = ((unsigned)wy0 < WROWS) && ((unsigned)wy1 < WROWS);
    okmask |= ((int)ok) << k;
    int wy0c = min(max(wy0, 0), WROWS - 1);
    int wy1c = min(max(wy1, 0), WROWS - 1);
    idxAB[k] = (wy0c * 68 + xm) | ((wy1c * 68 + xm) << 16);
    w01[k] = __floats2half2_rn((1.f - dy) * (1.f - dx) * vy0 * vx0,
                               (1.f - dy) * dx * vy0 * vx1);
    w23[k] = __floats2half2_rn(dy * (1.f - dx) * vy1 * vx0,
                               dy * dx * vy1 * vx1);
  }

  const int c0 = csplit * 48;
  const float* xq0 = x + ((size_t)b * C + c0) * HW;

  for (int q = 0; q < 12; ++q) {
    const float* xq = xq0 + (size_t)(q * 4) * HW;
    __syncthreads();
    for (int i = tid; i < WROWS * 64; i += 256) {
      int rr = i >> 6;
      int col = i & 63;
      int ly = lo + rr;
      uint2 p = make_uint2(0u, 0u);
      if (ly >= 0 && ly < H) {
        const float* xp = xq + (size_t)ly * W + col;
        p.x = h2_bits(__floats2half2_rn(xp[0], xp[HW]));
        p.y = h2_bits(__floats2half2_rn(xp[2 * HW], xp[3 * HW]));
      }
      S[rr * 68 + col + 1] = p;
    }
    __syncthreads();

    int cp0 = (c0 + q * 4) >> 1;
    __half2 acc01 = __float2half2_rn(0.f);
    __half2 acc23 = __float2half2_rn(0.f);
#pragma unroll
    for (int k = 0; k < KK; ++k) {
      int ia = idxAB[k] & 0xFFFF;
      int ib = idxAB[k] >> 16;
      uint2 u00 = S[ia], u01 = S[ia + 1];
      uint2 u10 = S[ib], u11 = S[ib + 1];
      __half2 b0 = __half2half2(__low2half(w01[k]));
      __half2 b1 = __half2half2(__high2half(w01[k]));
      __half2 b2 = __half2half2(__low2half(w23[k]));
      __half2 b3 = __half2half2(__high2half(w23[k]));
      __half2 t01 = __hmul2(b0, bc_h2(u00.x));
      t01 = __hfma2(b1, bc_h2(u01.x), t01);
      t01 = __hfma2(b2, bc_h2(u10.x), t01);
      t01 = __hfma2(b3, bc_h2(u11.x), t01);
      __half2 t23 = __hmul2(b0, bc_h2(u00.y));
      t23 = __hfma2(b1, bc_h2(u01.y), t23);
      t23 = __hfma2(b2, bc_h2(u10.y), t23);
      t23 = __hfma2(b3, bc_h2(u11.y), t23);
      acc01 = __hfma2(bc_h2(wdh[cp0 * KK + k]), t01, acc01);
      acc23 = __hfma2(bc_h2(wdh[(cp0 + 1) * KK + k]), t23, acc23);
    }
    size_t obase = ((size_t)b * 96 + cp0) * HW + (size_t)h * W + w;
    dwp[obase] = h2_bits(acc01);
    dwp[obase + HW] = h2_bits(acc23);
  }

  // cold fixup: any tap outside the staged window -> exact recompute (global)
  if (__builtin_expect(okmask != 0x1FF, 0)) {
#pragma unroll 1
    for (int q = 0; q < 12; ++q) {
      int cq = c0 + q * 4;
      int cp0 = cq >> 1;
      const float* xq = xq0 + (size_t)(q * 4) * HW;
      float a0 = 0.f, a1 = 0.f, a2 = 0.f, a3 = 0.f;
#pragma unroll 1
      for (int k = 0; k < KK; ++k) {
        int ki = k / 3, kj = k % 3;
        size_t oyi = (size_t)(2 * k) * HW;
        size_t oxi = (size_t)(2 * k + 1) * HW;
        float oy = pb[oyi] + pb[oyi + PST] + pb[oyi + 2 * PST] + b_off[2 * k];
        float ox = pb[oxi] + pb[oxi + PST] + pb[oxi + 2 * PST] + b_off[2 * k + 1];
        float py = (float)(h - 1 + ki) + oy;
        float px = (float)(w - 1 + kj) + ox;
        float y0f = floorf(py), x0f = floorf(px);
        float dy = py - y0f, dx = px - x0f;
        int y0 = (int)y0f, x0 = (int)x0f;
        int y1 = y0 + 1, x1 = x0 + 1;
        float vy0 = (y0 >= 0 && y0 < H) ? 1.f : 0.f;
        float vy1 = (y1 >= 0 && y1 < H) ? 1.f : 0.f;
        float vx0 = (x0 >= 0 && x0 < W) ? 1.f : 0.f;
        float vx1 = (x1 >= 0 && x1 < W) ? 1.f : 0.f;
        int y0c = min(max(y0, 0), H - 1);
        int y1c = min(max(y1, 0), H - 1);
        int xc0 = min(max(x0, 0), W - 1);
        int xc1 = min(max(x1, 0), W - 1);
        float w0 = (1.f - dy) * (1.f - dx) * vy0 * vx0;
        float w1 = (1.f - dy) * dx * vy0 * vx1;
        float w2 = dy * (1.f - dx) * vy1 * vx0;
        float w3 = dy * dx * vy1 * vx1;
        int a00 = y0c * W + xc0, a01 = y0c * W + xc1;
        int a10 = y1c * W + xc0, a11 = y1c * W + xc1;
        __half2 wd01 = bc_h2(wdh[cp0 * KK + k]);
        __half2 wd23 = bc_h2(wdh[(cp0 + 1) * KK + k]);
        const float* p0 = xq;
        const float* p1 = xq + HW;
        const float* p2 = xq + 2 * HW;
        const float* p3 = xq + 3 * HW;
        float t0 = fmaf(w3, p0[a11], fmaf(w2, p0[a10], fmaf(w1, p0[a01], w0 * p0[a00])));
        float t1 = fmaf(w3, p1[a11], fmaf(w2, p1[a10], fmaf(w1, p1[a01], w0 * p1[a00])));
        float t2 = fmaf(w3, p2[a11], fmaf(w2, p2[a10], fmaf(w1, p2[a01], w0 * p2[a00])));
        float t3 = fmaf(w3, p3[a11], fmaf(w2, p3[a10], fmaf(w1, p3[a01], w0 * p3[a00])));
        a0 = fmaf(__low2float(wd01), t0, a0);
        a1 = fmaf(__high2float(wd01), t1, a1);
        a2 = fmaf(__low2float(wd23), t2, a2);
        a3 = fmaf(__high2float(wd23), t3, a3);
      }
      size_t obase = ((size_t)b * 96 + cp0) * HW + (size_t)h * W + w;
      dwp[obase] = h2_bits(__floats2half2_rn(a0, a1));
      dwp[obase + HW] = h2_bits(__floats2half2_rn(a2, a3));
    }
  }
}

// ---------------------------------------------------------------------------
// Kernel C: pointwise 1x1 conv via f16 MFMA  [unchanged]
// ---------------------------------------------------------------------------
__global__ __launch_bounds__(256) void pointwise_mfma(
    const unsigned* __restrict__ dwp, const unsigned* __restrict__ wPW,
    float* __restrict__ out) {
  int blk = blockIdx.x;
  int nt = blk & 63;
  int mt = (blk >> 6) % 3;
  int b = blk / 192;
  int n0 = nt * 64;
  int m0 = mt * 128;
  int tid = threadIdx.x;
  int lane = tid & 63;
  int wv = tid >> 6;
  int wm = wv >> 1;
  int wn = wv & 1;
  int lpx = lane & 15;
  int lkg = lane >> 4;

  __shared__ __align__(16) unsigned sA[128 * 22];
  __shared__ __align__(16) unsigned sB[64 * 22];

  f32x4 acc[4][2];
#pragma unroll
  for (int mf = 0; mf < 4; ++mf)
#pragma unroll
    for (int nf = 0; nf < 2; ++nf) acc[mf][nf] = (f32x4){0.f, 0.f, 0.f, 0.f};

  const unsigned* dwb = dwp + (size_t)b * 96 * HW + n0;

  for (int chunk = 0; chunk < 6; ++chunk) {
    int kp0 = chunk * 16;
    __syncthreads();
#pragma unroll
    for (int t = 0; t < 8; ++t) {
      int i = t * 256 + tid;
      int m = i >> 4;
      int cd = i & 15;
      sA[m * 22 + cd] = wPW[(size_t)(m0 + m) * 96 + kp0 + cd];
    }
#pragma unroll
    for (int t = 0; t < 4; ++t) {
      int i = t * 256 + tid;
      int kp = i >> 6;
      int px = i & 63;
      sB[px * 22 + kp] = dwb[(size_t)(kp0 + kp) * HW + px];
    }
    __syncthreads();

    half8 af[4];
#pragma unroll
    for (int mf = 0; mf < 4; ++mf) {
      int m = wm * 64 + mf * 16 + lpx;
      af[mf] = ld_frag8h(&sA[m * 22 + lkg * 4]);
    }
    half8 bf[2];
#pragma unroll
    for (int nf = 0; nf < 2; ++nf) {
      int px = wn * 32 + nf * 16 + lpx;
      bf[nf] = ld_frag8h(&sB[px * 22 + lkg * 4]);
    }
#pragma unroll
    for (int mf = 0; mf < 4; ++mf)
#pragma unroll
      for (int nf = 0; nf < 2; ++nf)
        acc[mf][nf] = __builtin_amdgcn_mfma_f32_16x16x32_f16(
            af[mf], bf[nf], acc[mf][nf], 0, 0, 0);
  }

#pragma unroll
  for (int mf = 0; mf < 4; ++mf) {
#pragma unroll
    for (int nf = 0; nf < 2; ++nf) {
      int px = n0 + wn * 32 + nf * 16 + lpx;
#pragma unroll
      for (int j = 0; j < 4; ++j) {
        int o = m0 + wm * 64 + mf * 16 + lkg * 4 + j;
        out[((size_t)b * COUT + o) * HW + px] = acc[mf][nf][j];
      }
    }
  }
}

// ---------------------------------------------------------------------------
extern "C" void kernel_launch(void* const* d_in, const int* in_sizes, int n_in,
                              void* d_out, int out_size, void* d_ws,
                              size_t ws_size, hipStream_t stream) {
  const float* x = (const float*)d_in[0];
  const float* w_off = (const float*)d_in[1];
  const float* b_off = (const float*)d_in[2];
  const float* w_dw = (const float*)d_in[3];
  const float* w_pw = (const float*)d_in[4];
  float* out = (float*)d_out;

  char* ws = (char*)d_ws;
  float* part = (float*)ws;                         // 3 x 4.72 MB = 14.16 MB
  unsigned* dwp = (unsigned*)(ws + 14155776);       // 25.17 MB
  unsigned short* wA = (unsigned short*)(ws + 14155776 + 25165824);        // 110 KB
  unsigned* wPW = (unsigned*)(ws + 14155776 + 25165824 + 110592);          // 147 KB
  unsigned* wdh = (unsigned*)(ws + 14155776 + 25165824 + 110592 + 147456); // 3.5 KB

  int prep_n = 9 * 32 * C + COUT * (C / 2) + (C / 2) * KK;
  prep_weights<<<(prep_n + 255) / 256, 256, 0, stream>>>(w_off, w_pw, w_dw, wA,
                                                         wPW, wdh);
  offset_mfma<<<BB * 16 * 3, 512, 0, stream>>>(x, wA, part);
  sample_dw<<<BB * 16 * 4, 256, 0, stream>>>(x, part, b_off, wdh, dwp);
  pointwise_mfma<<<BB * 3 * 64, 256, 0, stream>>>(dwp, wPW, out);
}

// Round 18
// 101.439 us; speedup vs baseline: 1.0257x; 1.0257x over previous
//
#include <hip/hip_runtime.h>
#include <hip/hip_fp16.h>

#define BB 16
#define C 192
#define COUT 384
#define H 64
#define W 64
#define HW (H * W)
#define KK 9
#define OFFC 18
#define WROWS 18  // sample_dw staged window rows: [h0-7, h0+11)

typedef __attribute__((ext_vector_type(8))) short short8;
typedef __attribute__((ext_vector_type(8))) _Float16 half8;
typedef __attribute__((ext_vector_type(4))) float f32x4;

// round-to-nearest-even f32 -> bf16 bits
static __device__ inline unsigned short f2bf(float f) {
  union { float f; unsigned u; } v;
  v.f = f;
  unsigned r = v.u + 0x7FFF + ((v.u >> 16) & 1);
  return (unsigned short)(r >> 16);
}

union H2U { __half2 h; unsigned u; };

static __device__ inline __half2 bc_h2(unsigned u) {
  H2U v; v.u = u; return v.h;
}
static __device__ inline unsigned h2_bits(__half2 h) {
  H2U v; v.h = h; return v.u;
}

static __device__ inline half8 ld_frag8h(const unsigned* p) {
  union { unsigned u[4]; half8 s; } v;
  uint2 a = *(const uint2*)p;
  uint2 b = *(const uint2*)(p + 2);
  v.u[0] = a.x; v.u[1] = a.y; v.u[2] = b.x; v.u[3] = b.y;
  return v.s;
}

// ---------------------------------------------------------------------------
// Merged prep: wA (bf16, offset conv) + wPW (f16 c-pairs) + wdh (f16 dw pairs)
// ---------------------------------------------------------------------------
__global__ __launch_bounds__(256) void prep_weights(
    const float* __restrict__ w_off, const float* __restrict__ w_pw,
    const float* __restrict__ w_dw, unsigned short* __restrict__ wA,
    unsigned* __restrict__ wPW, unsigned* __restrict__ wdh) {
  int idx = blockIdx.x * 256 + threadIdx.x;
  if (idx < 9 * 32 * C) {
    int k = idx / (32 * C);
    int rem = idx % (32 * C);
    int o = rem / C;
    int c = rem % C;
    float v = (o < OFFC) ? w_off[((size_t)o * C + c) * KK + k] : 0.f;
    wA[idx] = f2bf(v);
    return;
  }
  int i2 = idx - 9 * 32 * C;
  if (i2 < COUT * (C / 2)) {
    float2 v = *(const float2*)(w_pw + (size_t)i2 * 2);
    wPW[i2] = h2_bits(__floats2half2_rn(v.x, v.y));
    return;
  }
  int i3 = i2 - COUT * (C / 2);
  if (i3 < (C / 2) * KK) {
    int cp = i3 / KK;
    int k = i3 % KK;
    wdh[i3] = h2_bits(
        __floats2half2_rn(w_dw[(size_t)(2 * cp) * KK + k],
                          w_dw[(size_t)(2 * cp + 1) * KK + k]));
  }
}

// ---------------------------------------------------------------------------
// Kernel A: offset conv via bf16 MFMA [r15 config — best measured].
// 3-way K-split; each block loops two 32-ch chunks with LDS restage.
// grid = B * 8 rowtiles(8 rows) * 3 = 384 blocks, 512 thr = 8 waves.
// Plain coalesced stores to part[ks]; no atomics, no RMW.
// ---------------------------------------------------------------------------
__global__ __launch_bounds__(512) void offset_mfma(
    const float* __restrict__ x, const unsigned short* __restrict__ wA,
    float* __restrict__ part) {
  int blk = blockIdx.x;
  int ks = blk % 3;
  int rowtile = (blk / 3) & 7;
  int b = blk / 24;
  int h0 = rowtile * 8;
  int tid = threadIdx.x;
  int lane = tid & 63;
  int wv = tid >> 6;    // wave id = output row offset (0..7)
  int lpx = lane & 15;
  int lkg = lane >> 4;

  __shared__ __align__(16) unsigned short wlds[9 * 32 * 40];   // 23040 B
  __shared__ __align__(16) unsigned short xlds[10 * 68 * 40];  // 54400 B

  for (int i = tid; i < 10 * 2 * 16; i += 512) {
    int rr = i >> 5;
    int side = (i >> 4) & 1;
    int cd = i & 15;
    int m = side ? 65 : 0;
    ((unsigned*)xlds)[(rr * 68 + m) * 20 + cd] = 0u;
  }

  f32x4 acc[4][2];
#pragma unroll
  for (int nt = 0; nt < 4; ++nt)
#pragma unroll
    for (int m = 0; m < 2; ++m) acc[nt][m] = (f32x4){0.f, 0.f, 0.f, 0.f};

  const float* xb = x + (size_t)b * C * HW;

  for (int ch2 = 0; ch2 < 2; ++ch2) {
    int c0 = (ks * 2 + ch2) * 32;
    __syncthreads();

    for (int t = 0; t < 3; ++t) {
      int i = t * 512 + tid;
      if (i < 1152) {
        int ko = i >> 2;
        int cq = i & 3;
        const unsigned* src = (const unsigned*)wA + ko * 96 + (c0 >> 1) + cq * 4;
        uint2 a = *(const uint2*)src;
        uint2 bq = *(const uint2*)(src + 2);
        unsigned* dst = (unsigned*)wlds + ko * 20 + cq * 4;
        dst[0] = a.x; dst[1] = a.y; dst[2] = bq.x; dst[3] = bq.y;
      }
    }

#pragma unroll
    for (int t = 0; t < 5; ++t) {
      int i = t * 512 + tid;  // 2560 units
      int cc2 = i / 160;
      int rem = i % 160;
      int rr = rem >> 4;
      int col0 = (rem & 15) * 4;
      int ly = h0 + rr - 1;
      unsigned d0 = 0, d1 = 0, d2 = 0, d3 = 0;
      if (ly >= 0 && ly < H) {
        const float* xp = xb + (size_t)(c0 + 2 * cc2) * HW + ly * W + col0;
        float4 a = *(const float4*)xp;
        float4 bq = *(const float4*)(xp + HW);
        d0 = ((unsigned)f2bf(bq.x) << 16) | (unsigned)f2bf(a.x);
        d1 = ((unsigned)f2bf(bq.y) << 16) | (unsigned)f2bf(a.y);
        d2 = ((unsigned)f2bf(bq.z) << 16) | (unsigned)f2bf(a.z);
        d3 = ((unsigned)f2bf(bq.w) << 16) | (unsigned)f2bf(a.w);
      }
      unsigned* xd = (unsigned*)xlds;
      int base = (rr * 68 + col0 + 1) * 20 + cc2;
      xd[base] = d0;
      xd[base + 20] = d1;
      xd[base + 40] = d2;
      xd[base + 60] = d3;
    }
    __syncthreads();

#pragma unroll
    for (int k = 0; k < 9; ++k) {
      int ki = k / 3, kj = k % 3;
      short8 af0 = *(const short8*)&wlds[(k * 32 + lpx) * 40 + lkg * 8];
      short8 af1 = *(const short8*)&wlds[(k * 32 + 16 + lpx) * 40 + lkg * 8];
#pragma unroll
      for (int nt = 0; nt < 4; ++nt) {
        short8 bf =
            *(const short8*)&xlds[((wv + ki) * 68 + nt * 16 + lpx + kj) * 40 +
                                  lkg * 8];
        acc[nt][0] = __builtin_amdgcn_mfma_f32_16x16x32_bf16(af0, bf,
                                                             acc[nt][0], 0, 0, 0);
        acc[nt][1] = __builtin_amdgcn_mfma_f32_16x16x32_bf16(af1, bf,
                                                             acc[nt][1], 0, 0, 0);
      }
    }
  }

  int h = h0 + wv;
  float* pb = part + ((size_t)ks * BB + b) * OFFC * HW + (size_t)h * W;
#pragma unroll
  for (int nt = 0; nt < 4; ++nt) {
    int col = nt * 16 + lpx;
#pragma unroll
    for (int j = 0; j < 4; ++j) {
      int o = lkg * 4 + j;
      pb[(size_t)o * HW + col] = acc[nt][0][j];
    }
    if (lkg == 0) {
#pragma unroll
      for (int j = 0; j < 2; ++j) {
        pb[(size_t)(16 + j) * HW + col] = acc[nt][1][j];
      }
    }
  }
}

// ---------------------------------------------------------------------------
// Reduce 3 partials + bias -> offs (float4; reads part ONLY, writes offs once)
// ---------------------------------------------------------------------------
__global__ __launch_bounds__(256) void offset_reduce(
    const float* __restrict__ part, const float* __restrict__ b_off,
    float* __restrict__ offs) {
  int idx = blockIdx.x * 256 + threadIdx.x;  // float4 index
  const int N4 = BB * OFFC * HW / 4;
  if (idx >= N4) return;
  int o = (idx >> 10) % OFFC;  // HW/4 = 1024
  const size_t stride = (size_t)BB * OFFC * HW / 4;
  float4 p0 = ((const float4*)part)[idx];
  float4 p1 = ((const float4*)part)[idx + stride];
  float4 p2 = ((const float4*)part)[idx + 2 * stride];
  float bo = b_off[o];
  float4 r;
  r.x = p0.x + p1.x + p2.x + bo;
  r.y = p0.y + p1.y + p2.y + bo;
  r.z = p0.z + p1.z + p2.z + bo;
  r.w = p0.w + p1.w + p2.w + bo;
  ((float4*)offs)[idx] = r;
}

// ---------------------------------------------------------------------------
// Kernel B: bilinear sample + depthwise -> dwp[B][96][HW] packed f16 c-pairs.
// r15 structure (csplit 8, 256 thr, grid 2048) + TWO-QUAD PHASES:
// stage 8 channels into S[2] per barrier pair (3 phases, barriers 12->6),
// tap loop computes both quads per k (8 independent LDS reads -> 2x MLP).
// ---------------------------------------------------------------------------
__global__ __launch_bounds__(256) void sample_dw(
    const float* __restrict__ x, const float* __restrict__ offs,
    const unsigned* __restrict__ wdh, unsigned* __restrict__ dwp) {
  int blk = blockIdx.x;
  int csplit = blk & 7;
  int rowtile = (blk >> 3) & 15;
  int b = blk >> 7;
  int tid = threadIdx.x;
  int r = tid >> 6;
  int w = tid & 63;
  int h0 = rowtile * 4;
  int h = h0 + r;
  int lo = h0 - 7;  // window rows [lo, lo+WROWS)

  __shared__ uint2 S[2][WROWS * 68];  // 2 x 9792 B

  // zero pad columns m in {0,65,66,67} for both buffers
  for (int i = tid; i < 2 * WROWS * 4; i += 256) {
    int bf = i / (WROWS * 4);
    int rem = i % (WROWS * 4);
    int rr = rem >> 2;
    int p = rem & 3;
    int m = (p == 0) ? 0 : 64 + p;
    S[bf][rr * 68 + m] = make_uint2(0u, 0u);
  }

  // per-pixel tap setup (channel-independent), packed state
  const float* ob = offs + (size_t)b * OFFC * HW + (size_t)h * W + w;
  int idxAB[KK];
  __half2 w01[KK], w23[KK];
  int okmask = 0;
#pragma unroll
  for (int k = 0; k < KK; ++k) {
    int ki = k / 3, kj = k % 3;
    float oy = ob[(size_t)(2 * k) * HW];
    float ox = ob[(size_t)(2 * k + 1) * HW];
    float py = (float)(h - 1 + ki) + oy;
    float px = (float)(w - 1 + kj) + ox;
    float y0f = floorf(py), x0f = floorf(px);
    float dy = py - y0f, dx = px - x0f;
    int y0 = (int)y0f, x0 = (int)x0f;
    int y1 = y0 + 1, x1 = x0 + 1;
    float vy0 = (y0 >= 0 && y0 < H) ? 1.f : 0.f;
    float vy1 = (y1 >= 0 && y1 < H) ? 1.f : 0.f;
    float vx0 = (x0 >= 0 && x0 < W) ? 1.f : 0.f;
    float vx1 = (x1 >= 0 && x1 < W) ? 1.f : 0.f;
    int y0c = min(max(y0, 0), H - 1);
    int y1c = min(max(y1, 0), H - 1);
    int xm = min(max(x0, -1), 65) + 1;  // plane cols (xm, xm+1)
    int wy0 = y0c - lo, wy1 = y1c - lo;
    bool ok = ((unsigned)wy0 < WROWS) && ((unsigned)wy1 < WROWS);
    okmask |= ((int)ok) << k;
    int wy0c = min(max(wy0, 0), WROWS - 1);
    int wy1c = min(max(wy1, 0), WROWS - 1);
    idxAB[k] = (wy0c * 68 + xm) | ((wy1c * 68 + xm) << 16);
    w01[k] = __floats2half2_rn((1.f - dy) * (1.f - dx) * vy0 * vx0,
                               (1.f - dy) * dx * vy0 * vx1);
    w23[k] = __floats2half2_rn(dy * (1.f - dx) * vy1 * vx0,
                               dy * dx * vy1 * vx1);
  }

  const int c0 = csplit * 24;
  const float* xq0 = x + ((size_t)b * C + c0) * HW;

  for (int qq = 0; qq < 3; ++qq) {
    __syncthreads();  // prior phase's reads done before overwrite
    // stage two 4-channel quads (8 channels) into S[0], S[1]
    for (int i = tid; i < 2 * WROWS * 64; i += 256) {
      int bf = i / (WROWS * 64);
      int rem = i % (WROWS * 64);
      int rr = rem >> 6;
      int col = rem & 63;
      int ly = lo + rr;
      uint2 p = make_uint2(0u, 0u);
      if (ly >= 0 && ly < H) {
        const float* xp =
            xq0 + (size_t)(qq * 8 + bf * 4) * HW + (size_t)ly * W + col;
        p.x = h2_bits(__floats2half2_rn(xp[0], xp[HW]));
        p.y = h2_bits(__floats2half2_rn(xp[2 * HW], xp[3 * HW]));
      }
      S[bf][rr * 68 + col + 1] = p;
    }
    __syncthreads();

    int cp0 = (c0 + qq * 8) >> 1;  // quad0 pairs: cp0,cp0+1; quad1: +2,+3
    __half2 a01_0 = __float2half2_rn(0.f);
    __half2 a23_0 = __float2half2_rn(0.f);
    __half2 a01_1 = __float2half2_rn(0.f);
    __half2 a23_1 = __float2half2_rn(0.f);
#pragma unroll
    for (int k = 0; k < KK; ++k) {
      int ia = idxAB[k] & 0xFFFF;
      int ib = idxAB[k] >> 16;
      __half2 b0 = __half2half2(__low2half(w01[k]));
      __half2 b1 = __half2half2(__high2half(w01[k]));
      __half2 b2 = __half2half2(__low2half(w23[k]));
      __half2 b3 = __half2half2(__high2half(w23[k]));
      uint2 p00 = S[0][ia], p01 = S[0][ia + 1];
      uint2 p10 = S[0][ib], p11 = S[0][ib + 1];
      uint2 q00 = S[1][ia], q01 = S[1][ia + 1];
      uint2 q10 = S[1][ib], q11 = S[1][ib + 1];
      __half2 t01 = __hmul2(b0, bc_h2(p00.x));
      t01 = __hfma2(b1, bc_h2(p01.x), t01);
      t01 = __hfma2(b2, bc_h2(p10.x), t01);
      t01 = __hfma2(b3, bc_h2(p11.x), t01);
      __half2 t23 = __hmul2(b0, bc_h2(p00.y));
      t23 = __hfma2(b1, bc_h2(p01.y), t23);
      t23 = __hfma2(b2, bc_h2(p10.y), t23);
      t23 = __hfma2(b3, bc_h2(p11.y), t23);
      __half2 s01 = __hmul2(b0, bc_h2(q00.x));
      s01 = __hfma2(b1, bc_h2(q01.x), s01);
      s01 = __hfma2(b2, bc_h2(q10.x), s01);
      s01 = __hfma2(b3, bc_h2(q11.x), s01);
      __half2 s23 = __hmul2(b0, bc_h2(q00.y));
      s23 = __hfma2(b1, bc_h2(q01.y), s23);
      s23 = __hfma2(b2, bc_h2(q10.y), s23);
      s23 = __hfma2(b3, bc_h2(q11.y), s23);
      a01_0 = __hfma2(bc_h2(wdh[(cp0 + 0) * KK + k]), t01, a01_0);
      a23_0 = __hfma2(bc_h2(wdh[(cp0 + 1) * KK + k]), t23, a23_0);
      a01_1 = __hfma2(bc_h2(wdh[(cp0 + 2) * KK + k]), s01, a01_1);
      a23_1 = __hfma2(bc_h2(wdh[(cp0 + 3) * KK + k]), s23, a23_1);
    }
    size_t obase = ((size_t)b * 96 + cp0) * HW + (size_t)h * W + w;
    dwp[obase] = h2_bits(a01_0);
    dwp[obase + HW] = h2_bits(a23_0);
    dwp[obase + 2 * HW] = h2_bits(a01_1);
    dwp[obase + 3 * HW] = h2_bits(a23_1);
  }

  // cold fixup: any tap outside the staged window -> exact recompute (global)
  if (__builtin_expect(okmask != 0x1FF, 0)) {
#pragma unroll 1
    for (int q = 0; q < 6; ++q) {
      int cq = c0 + q * 4;
      int cp0 = cq >> 1;
      const float* xq = xq0 + (size_t)(q * 4) * HW;
      float a0 = 0.f, a1 = 0.f, a2 = 0.f, a3 = 0.f;
#pragma unroll 1
      for (int k = 0; k < KK; ++k) {
        int ki = k / 3, kj = k % 3;
        float oy = ob[(size_t)(2 * k) * HW];
        float ox = ob[(size_t)(2 * k + 1) * HW];
        float py = (float)(h - 1 + ki) + oy;
        float px = (float)(w - 1 + kj) + ox;
        float y0f = floorf(py), x0f = floorf(px);
        float dy = py - y0f, dx = px - x0f;
        int y0 = (int)y0f, x0 = (int)x0f;
        int y1 = y0 + 1, x1 = x0 + 1;
        float vy0 = (y0 >= 0 && y0 < H) ? 1.f : 0.f;
        float vy1 = (y1 >= 0 && y1 < H) ? 1.f : 0.f;
        float vx0 = (x0 >= 0 && x0 < W) ? 1.f : 0.f;
        float vx1 = (x1 >= 0 && x1 < W) ? 1.f : 0.f;
        int y0c = min(max(y0, 0), H - 1);
        int y1c = min(max(y1, 0), H - 1);
        int xc0 = min(max(x0, 0), W - 1);
        int xc1 = min(max(x1, 0), W - 1);
        float w0 = (1.f - dy) * (1.f - dx) * vy0 * vx0;
        float w1 = (1.f - dy) * dx * vy0 * vx1;
        float w2 = dy * (1.f - dx) * vy1 * vx0;
        float w3 = dy * dx * vy1 * vx1;
        int a00 = y0c * W + xc0, a01 = y0c * W + xc1;
        int a10 = y1c * W + xc0, a11 = y1c * W + xc1;
        __half2 wd01 = bc_h2(wdh[cp0 * KK + k]);
        __half2 wd23 = bc_h2(wdh[(cp0 + 1) * KK + k]);
        const float* p0 = xq;
        const float* p1 = xq + HW;
        const float* p2 = xq + 2 * HW;
        const float* p3 = xq + 3 * HW;
        float t0 = fmaf(w3, p0[a11], fmaf(w2, p0[a10], fmaf(w1, p0[a01], w0 * p0[a00])));
        float t1 = fmaf(w3, p1[a11], fmaf(w2, p1[a10], fmaf(w1, p1[a01], w0 * p1[a00])));
        float t2 = fmaf(w3, p2[a11], fmaf(w2, p2[a10], fmaf(w1, p2[a01], w0 * p2[a00])));
        float t3 = fmaf(w3, p3[a11], fmaf(w2, p3[a10], fmaf(w1, p3[a01], w0 * p3[a00])));
        a0 = fmaf(__low2float(wd01), t0, a0);
        a1 = fmaf(__high2float(wd01), t1, a1);
        a2 = fmaf(__low2float(wd23), t2, a2);
        a3 = fmaf(__high2float(wd23), t3, a3);
      }
      size_t obase = ((size_t)b * 96 + cp0) * HW + (size_t)h * W + w;
      dwp[obase] = h2_bits(__floats2half2_rn(a0, a1));
      dwp[obase + HW] = h2_bits(__floats2half2_rn(a2, a3));
    }
  }
}

// ---------------------------------------------------------------------------
// Kernel C: pointwise 1x1 conv via f16 MFMA  [unchanged]
// ---------------------------------------------------------------------------
__global__ __launch_bounds__(256) void pointwise_mfma(
    const unsigned* __restrict__ dwp, const unsigned* __restrict__ wPW,
    float* __restrict__ out) {
  int blk = blockIdx.x;
  int nt = blk & 63;
  int mt = (blk >> 6) % 3;
  int b = blk / 192;
  int n0 = nt * 64;
  int m0 = mt * 128;
  int tid = threadIdx.x;
  int lane = tid & 63;
  int wv = tid >> 6;
  int wm = wv >> 1;
  int wn = wv & 1;
  int lpx = lane & 15;
  int lkg = lane >> 4;

  __shared__ __align__(16) unsigned sA[128 * 22];
  __shared__ __align__(16) unsigned sB[64 * 22];

  f32x4 acc[4][2];
#pragma unroll
  for (int mf = 0; mf < 4; ++mf)
#pragma unroll
    for (int nf = 0; nf < 2; ++nf) acc[mf][nf] = (f32x4){0.f, 0.f, 0.f, 0.f};

  const unsigned* dwb = dwp + (size_t)b * 96 * HW + n0;

  for (int chunk = 0; chunk < 6; ++chunk) {
    int kp0 = chunk * 16;
    __syncthreads();
#pragma unroll
    for (int t = 0; t < 8; ++t) {
      int i = t * 256 + tid;
      int m = i >> 4;
      int cd = i & 15;
      sA[m * 22 + cd] = wPW[(size_t)(m0 + m) * 96 + kp0 + cd];
    }
#pragma unroll
    for (int t = 0; t < 4; ++t) {
      int i = t * 256 + tid;
      int kp = i >> 6;
      int px = i & 63;
      sB[px * 22 + kp] = dwb[(size_t)(kp0 + kp) * HW + px];
    }
    __syncthreads();

    half8 af[4];
#pragma unroll
    for (int mf = 0; mf < 4; ++mf) {
      int m = wm * 64 + mf * 16 + lpx;
      af[mf] = ld_frag8h(&sA[m * 22 + lkg * 4]);
    }
    half8 bf[2];
#pragma unroll
    for (int nf = 0; nf < 2; ++nf) {
      int px = wn * 32 + nf * 16 + lpx;
      bf[nf] = ld_frag8h(&sB[px * 22 + lkg * 4]);
    }
#pragma unroll
    for (int mf = 0; mf < 4; ++mf)
#pragma unroll
      for (int nf = 0; nf < 2; ++nf)
        acc[mf][nf] = __builtin_amdgcn_mfma_f32_16x16x32_f16(
            af[mf], bf[nf], acc[mf][nf], 0, 0, 0);
  }

#pragma unroll
  for (int mf = 0; mf < 4; ++mf) {
#pragma unroll
    for (int nf = 0; nf < 2; ++nf) {
      int px = n0 + wn * 32 + nf * 16 + lpx;
#pragma unroll
      for (int j = 0; j < 4; ++j) {
        int o = m0 + wm * 64 + mf * 16 + lkg * 4 + j;
        out[((size_t)b * COUT + o) * HW + px] = acc[mf][nf][j];
      }
    }
  }
}

// ---------------------------------------------------------------------------
extern "C" void kernel_launch(void* const* d_in, const int* in_sizes, int n_in,
                              void* d_out, int out_size, void* d_ws,
                              size_t ws_size, hipStream_t stream) {
  const float* x = (const float*)d_in[0];
  const float* w_off = (const float*)d_in[1];
  const float* b_off = (const float*)d_in[2];
  const float* w_dw = (const float*)d_in[3];
  const float* w_pw = (const float*)d_in[4];
  float* out = (float*)d_out;

  char* ws = (char*)d_ws;
  float* offs = (float*)ws;                       // 4.72 MB
  unsigned* dwp = (unsigned*)(ws + 4718592);      // 25.17 MB (holds partials first)
  unsigned short* wA = (unsigned short*)(ws + 4718592 + 25165824);       // 110 KB
  unsigned* wPW = (unsigned*)(ws + 4718592 + 25165824 + 110592);         // 147 KB
  unsigned* wdh = (unsigned*)(ws + 4718592 + 25165824 + 110592 + 147456);// 3.5 KB
  float* part = (float*)dwp;  // 3 x 4.72 MB partials, consumed before dwp written

  int prep_n = 9 * 32 * C + COUT * (C / 2) + (C / 2) * KK;
  prep_weights<<<(prep_n + 255) / 256, 256, 0, stream>>>(w_off, w_pw, w_dw, wA,
                                                         wPW, wdh);
  offset_mfma<<<BB * 8 * 3, 512, 0, stream>>>(x, wA, part);
  offset_reduce<<<(BB * OFFC * HW / 4 + 255) / 256, 256, 0, stream>>>(
      part, b_off, offs);
  sample_dw<<<BB * 16 * 8, 256, 0, stream>>>(x, offs, wdh, dwp);
  pointwise_mfma<<<BB * 3 * 64, 256, 0, stream>>>(dwp, wPW, out);
}

// Round 19
// 96.946 us; speedup vs baseline: 1.0733x; 1.0463x over previous
//
#include <hip/hip_runtime.h>
#include <hip/hip_fp16.h>

#define BB 16
#define C 192
#define COUT 384
#define H 64
#define W 64
#define HW (H * W)
#define KK 9
#define OFFC 18
#define WROWS 14  // sample_dw staged window rows: [h0-5, h0+9)

typedef __attribute__((ext_vector_type(8))) short short8;
typedef __attribute__((ext_vector_type(8))) _Float16 half8;
typedef __attribute__((ext_vector_type(4))) float f32x4;

// round-to-nearest-even f32 -> bf16 bits
static __device__ inline unsigned short f2bf(float f) {
  union { float f; unsigned u; } v;
  v.f = f;
  unsigned r = v.u + 0x7FFF + ((v.u >> 16) & 1);
  return (unsigned short)(r >> 16);
}

union H2U { __half2 h; unsigned u; };

static __device__ inline __half2 bc_h2(unsigned u) {
  H2U v; v.u = u; return v.h;
}
static __device__ inline unsigned h2_bits(__half2 h) {
  H2U v; v.h = h; return v.u;
}

static __device__ inline half8 ld_frag8h(const unsigned* p) {
  union { unsigned u[4]; half8 s; } v;
  uint2 a = *(const uint2*)p;
  uint2 b = *(const uint2*)(p + 2);
  v.u[0] = a.x; v.u[1] = a.y; v.u[2] = b.x; v.u[3] = b.y;
  return v.s;
}

// ---------------------------------------------------------------------------
// Merged prep: wA (bf16, offset conv) + wPW (f16 c-pairs) + wdh (f16 dw pairs)
// ---------------------------------------------------------------------------
__global__ __launch_bounds__(256) void prep_weights(
    const float* __restrict__ w_off, const float* __restrict__ w_pw,
    const float* __restrict__ w_dw, unsigned short* __restrict__ wA,
    unsigned* __restrict__ wPW, unsigned* __restrict__ wdh) {
  int idx = blockIdx.x * 256 + threadIdx.x;
  if (idx < 9 * 32 * C) {
    int k = idx / (32 * C);
    int rem = idx % (32 * C);
    int o = rem / C;
    int c = rem % C;
    float v = (o < OFFC) ? w_off[((size_t)o * C + c) * KK + k] : 0.f;
    wA[idx] = f2bf(v);
    return;
  }
  int i2 = idx - 9 * 32 * C;
  if (i2 < COUT * (C / 2)) {
    float2 v = *(const float2*)(w_pw + (size_t)i2 * 2);
    wPW[i2] = h2_bits(__floats2half2_rn(v.x, v.y));
    return;
  }
  int i3 = i2 - COUT * (C / 2);
  if (i3 < (C / 2) * KK) {
    int cp = i3 / KK;
    int k = i3 % KK;
    wdh[i3] = h2_bits(
        __floats2half2_rn(w_dw[(size_t)(2 * cp) * KK + k],
                          w_dw[(size_t)(2 * cp + 1) * KK + k]));
  }
}

// ---------------------------------------------------------------------------
// Kernel A: offset conv via bf16 MFMA [r15 config — best measured].
// 3-way K-split; each block loops two 32-ch chunks with LDS restage.
// grid = B * 8 rowtiles(8 rows) * 3 = 384 blocks, 512 thr = 8 waves.
// Plain coalesced stores to part[ks]; no atomics, no RMW.
// ---------------------------------------------------------------------------
__global__ __launch_bounds__(512) void offset_mfma(
    const float* __restrict__ x, const unsigned short* __restrict__ wA,
    float* __restrict__ part) {
  int blk = blockIdx.x;
  int ks = blk % 3;
  int rowtile = (blk / 3) & 7;
  int b = blk / 24;
  int h0 = rowtile * 8;
  int tid = threadIdx.x;
  int lane = tid & 63;
  int wv = tid >> 6;    // wave id = output row offset (0..7)
  int lpx = lane & 15;
  int lkg = lane >> 4;

  __shared__ __align__(16) unsigned short wlds[9 * 32 * 40];   // 23040 B
  __shared__ __align__(16) unsigned short xlds[10 * 68 * 40];  // 54400 B

  for (int i = tid; i < 10 * 2 * 16; i += 512) {
    int rr = i >> 5;
    int side = (i >> 4) & 1;
    int cd = i & 15;
    int m = side ? 65 : 0;
    ((unsigned*)xlds)[(rr * 68 + m) * 20 + cd] = 0u;
  }

  f32x4 acc[4][2];
#pragma unroll
  for (int nt = 0; nt < 4; ++nt)
#pragma unroll
    for (int m = 0; m < 2; ++m) acc[nt][m] = (f32x4){0.f, 0.f, 0.f, 0.f};

  const float* xb = x + (size_t)b * C * HW;

  for (int ch2 = 0; ch2 < 2; ++ch2) {
    int c0 = (ks * 2 + ch2) * 32;
    __syncthreads();

    for (int t = 0; t < 3; ++t) {
      int i = t * 512 + tid;
      if (i < 1152) {
        int ko = i >> 2;
        int cq = i & 3;
        const unsigned* src = (const unsigned*)wA + ko * 96 + (c0 >> 1) + cq * 4;
        uint2 a = *(const uint2*)src;
        uint2 bq = *(const uint2*)(src + 2);
        unsigned* dst = (unsigned*)wlds + ko * 20 + cq * 4;
        dst[0] = a.x; dst[1] = a.y; dst[2] = bq.x; dst[3] = bq.y;
      }
    }

#pragma unroll
    for (int t = 0; t < 5; ++t) {
      int i = t * 512 + tid;  // 2560 units
      int cc2 = i / 160;
      int rem = i % 160;
      int rr = rem >> 4;
      int col0 = (rem & 15) * 4;
      int ly = h0 + rr - 1;
      unsigned d0 = 0, d1 = 0, d2 = 0, d3 = 0;
      if (ly >= 0 && ly < H) {
        const float* xp = xb + (size_t)(c0 + 2 * cc2) * HW + ly * W + col0;
        float4 a = *(const float4*)xp;
        float4 bq = *(const float4*)(xp + HW);
        d0 = ((unsigned)f2bf(bq.x) << 16) | (unsigned)f2bf(a.x);
        d1 = ((unsigned)f2bf(bq.y) << 16) | (unsigned)f2bf(a.y);
        d2 = ((unsigned)f2bf(bq.z) << 16) | (unsigned)f2bf(a.z);
        d3 = ((unsigned)f2bf(bq.w) << 16) | (unsigned)f2bf(a.w);
      }
      unsigned* xd = (unsigned*)xlds;
      int base = (rr * 68 + col0 + 1) * 20 + cc2;
      xd[base] = d0;
      xd[base + 20] = d1;
      xd[base + 40] = d2;
      xd[base + 60] = d3;
    }
    __syncthreads();

#pragma unroll
    for (int k = 0; k < 9; ++k) {
      int ki = k / 3, kj = k % 3;
      short8 af0 = *(const short8*)&wlds[(k * 32 + lpx) * 40 + lkg * 8];
      short8 af1 = *(const short8*)&wlds[(k * 32 + 16 + lpx) * 40 + lkg * 8];
#pragma unroll
      for (int nt = 0; nt < 4; ++nt) {
        short8 bf =
            *(const short8*)&xlds[((wv + ki) * 68 + nt * 16 + lpx + kj) * 40 +
                                  lkg * 8];
        acc[nt][0] = __builtin_amdgcn_mfma_f32_16x16x32_bf16(af0, bf,
                                                             acc[nt][0], 0, 0, 0);
        acc[nt][1] = __builtin_amdgcn_mfma_f32_16x16x32_bf16(af1, bf,
                                                             acc[nt][1], 0, 0, 0);
      }
    }
  }

  int h = h0 + wv;
  float* pb = part + ((size_t)ks * BB + b) * OFFC * HW + (size_t)h * W;
#pragma unroll
  for (int nt = 0; nt < 4; ++nt) {
    int col = nt * 16 + lpx;
#pragma unroll
    for (int j = 0; j < 4; ++j) {
      int o = lkg * 4 + j;
      pb[(size_t)o * HW + col] = acc[nt][0][j];
    }
    if (lkg == 0) {
#pragma unroll
      for (int j = 0; j < 2; ++j) {
        pb[(size_t)(16 + j) * HW + col] = acc[nt][1][j];
      }
    }
  }
}

// ---------------------------------------------------------------------------
// Reduce 3 partials + bias -> offs (float4; reads part ONLY, writes offs once)
// ---------------------------------------------------------------------------
__global__ __launch_bounds__(256) void offset_reduce(
    const float* __restrict__ part, const float* __restrict__ b_off,
    float* __restrict__ offs) {
  int idx = blockIdx.x * 256 + threadIdx.x;  // float4 index
  const int N4 = BB * OFFC * HW / 4;
  if (idx >= N4) return;
  int o = (idx >> 10) % OFFC;  // HW/4 = 1024
  const size_t stride = (size_t)BB * OFFC * HW / 4;
  float4 p0 = ((const float4*)part)[idx];
  float4 p1 = ((const float4*)part)[idx + stride];
  float4 p2 = ((const float4*)part)[idx + 2 * stride];
  float bo = b_off[o];
  float4 r;
  r.x = p0.x + p1.x + p2.x + bo;
  r.y = p0.y + p1.y + p2.y + bo;
  r.z = p0.z + p1.z + p2.z + bo;
  r.w = p0.w + p1.w + p2.w + bo;
  ((float4*)offs)[idx] = r;
}

// ---------------------------------------------------------------------------
// Kernel B: bilinear sample + depthwise -> dwp[B][96][HW] packed f16 c-pairs.
// r18 structure (csplit 8, 256 thr, grid 2048, two-quad phases) with:
// - 14-row window (7-sigma; global fixup for outliers keeps correctness)
// - float4 staging: 4 cols x 4 ch per unit = 4 dwordx4 loads (was 16 dwords)
// ---------------------------------------------------------------------------
__global__ __launch_bounds__(256) void sample_dw(
    const float* __restrict__ x, const float* __restrict__ offs,
    const unsigned* __restrict__ wdh, unsigned* __restrict__ dwp) {
  int blk = blockIdx.x;
  int csplit = blk & 7;
  int rowtile = (blk >> 3) & 15;
  int b = blk >> 7;
  int tid = threadIdx.x;
  int r = tid >> 6;
  int w = tid & 63;
  int h0 = rowtile * 4;
  int h = h0 + r;
  int lo = h0 - 5;  // window rows [lo, lo+WROWS)

  __shared__ uint2 S[2][WROWS * 68];  // 2 x 7616 B

  // zero pad columns m in {0,65,66,67} for both buffers
  for (int i = tid; i < 2 * WROWS * 4; i += 256) {
    int bf = i / (WROWS * 4);
    int rem = i % (WROWS * 4);
    int rr = rem >> 2;
    int p = rem & 3;
    int m = (p == 0) ? 0 : 64 + p;
    S[bf][rr * 68 + m] = make_uint2(0u, 0u);
  }

  // per-pixel tap setup (channel-independent), packed state
  const float* ob = offs + (size_t)b * OFFC * HW + (size_t)h * W + w;
  int idxAB[KK];
  __half2 w01[KK], w23[KK];
  int okmask = 0;
#pragma unroll
  for (int k = 0; k < KK; ++k) {
    int ki = k / 3, kj = k % 3;
    float oy = ob[(size_t)(2 * k) * HW];
    float ox = ob[(size_t)(2 * k + 1) * HW];
    float py = (float)(h - 1 + ki) + oy;
    float px = (float)(w - 1 + kj) + ox;
    float y0f = floorf(py), x0f = floorf(px);
    float dy = py - y0f, dx = px - x0f;
    int y0 = (int)y0f, x0 = (int)x0f;
    int y1 = y0 + 1, x1 = x0 + 1;
    float vy0 = (y0 >= 0 && y0 < H) ? 1.f : 0.f;
    float vy1 = (y1 >= 0 && y1 < H) ? 1.f : 0.f;
    float vx0 = (x0 >= 0 && x0 < W) ? 1.f : 0.f;
    float vx1 = (x1 >= 0 && x1 < W) ? 1.f : 0.f;
    int y0c = min(max(y0, 0), H - 1);
    int y1c = min(max(y1, 0), H - 1);
    int xm = min(max(x0, -1), 65) + 1;  // plane cols (xm, xm+1)
    int wy0 = y0c - lo, wy1 = y1c - lo;
    bool ok = ((unsigned)wy0 < WROWS) && ((unsigned)wy1 < WROWS);
    okmask |= ((int)ok) << k;
    int wy0c = min(max(wy0, 0), WROWS - 1);
    int wy1c = min(max(wy1, 0), WROWS - 1);
    idxAB[k] = (wy0c * 68 + xm) | ((wy1c * 68 + xm) << 16);
    w01[k] = __floats2half2_rn((1.f - dy) * (1.f - dx) * vy0 * vx0,
                               (1.f - dy) * dx * vy0 * vx1);
    w23[k] = __floats2half2_rn(dy * (1.f - dx) * vy1 * vx0,
                               dy * dx * vy1 * vx1);
  }

  const int c0 = csplit * 24;
  const float* xq0 = x + ((size_t)b * C + c0) * HW;

  for (int qq = 0; qq < 3; ++qq) {
    __syncthreads();  // prior phase's reads done before overwrite
    // stage two 4-channel quads (8 ch) via float4 loads:
    // unit = (buffer, row, col-quad): 2 * 14 * 16 = 448 units
    for (int i = tid; i < 2 * WROWS * 16; i += 256) {
      int bf = i / (WROWS * 16);
      int rem = i % (WROWS * 16);
      int rr = rem >> 4;
      int col0 = (rem & 15) * 4;
      int ly = lo + rr;
      uint2 p0 = make_uint2(0u, 0u), p1 = p0, p2 = p0, p3 = p0;
      if (ly >= 0 && ly < H) {
        const float* xp =
            xq0 + (size_t)(qq * 8 + bf * 4) * HW + (size_t)ly * W + col0;
        float4 a0 = *(const float4*)xp;
        float4 a1 = *(const float4*)(xp + HW);
        float4 a2 = *(const float4*)(xp + 2 * HW);
        float4 a3 = *(const float4*)(xp + 3 * HW);
        p0.x = h2_bits(__floats2half2_rn(a0.x, a1.x));
        p0.y = h2_bits(__floats2half2_rn(a2.x, a3.x));
        p1.x = h2_bits(__floats2half2_rn(a0.y, a1.y));
        p1.y = h2_bits(__floats2half2_rn(a2.y, a3.y));
        p2.x = h2_bits(__floats2half2_rn(a0.z, a1.z));
        p2.y = h2_bits(__floats2half2_rn(a2.z, a3.z));
        p3.x = h2_bits(__floats2half2_rn(a0.w, a1.w));
        p3.y = h2_bits(__floats2half2_rn(a2.w, a3.w));
      }
      uint2* dst = &S[bf][rr * 68 + col0 + 1];
      dst[0] = p0;
      dst[1] = p1;
      dst[2] = p2;
      dst[3] = p3;
    }
    __syncthreads();

    int cp0 = (c0 + qq * 8) >> 1;  // quad0 pairs: cp0,cp0+1; quad1: +2,+3
    __half2 a01_0 = __float2half2_rn(0.f);
    __half2 a23_0 = __float2half2_rn(0.f);
    __half2 a01_1 = __float2half2_rn(0.f);
    __half2 a23_1 = __float2half2_rn(0.f);
#pragma unroll
    for (int k = 0; k < KK; ++k) {
      int ia = idxAB[k] & 0xFFFF;
      int ib = idxAB[k] >> 16;
      __half2 b0 = __half2half2(__low2half(w01[k]));
      __half2 b1 = __half2half2(__high2half(w01[k]));
      __half2 b2 = __half2half2(__low2half(w23[k]));
      __half2 b3 = __half2half2(__high2half(w23[k]));
      uint2 p00 = S[0][ia], p01 = S[0][ia + 1];
      uint2 p10 = S[0][ib], p11 = S[0][ib + 1];
      uint2 q00 = S[1][ia], q01 = S[1][ia + 1];
      uint2 q10 = S[1][ib], q11 = S[1][ib + 1];
      __half2 t01 = __hmul2(b0, bc_h2(p00.x));
      t01 = __hfma2(b1, bc_h2(p01.x), t01);
      t01 = __hfma2(b2, bc_h2(p10.x), t01);
      t01 = __hfma2(b3, bc_h2(p11.x), t01);
      __half2 t23 = __hmul2(b0, bc_h2(p00.y));
      t23 = __hfma2(b1, bc_h2(p01.y), t23);
      t23 = __hfma2(b2, bc_h2(p10.y), t23);
      t23 = __hfma2(b3, bc_h2(p11.y), t23);
      __half2 s01 = __hmul2(b0, bc_h2(q00.x));
      s01 = __hfma2(b1, bc_h2(q01.x), s01);
      s01 = __hfma2(b2, bc_h2(q10.x), s01);
      s01 = __hfma2(b3, bc_h2(q11.x), s01);
      __half2 s23 = __hmul2(b0, bc_h2(q00.y));
      s23 = __hfma2(b1, bc_h2(q01.y), s23);
      s23 = __hfma2(b2, bc_h2(q10.y), s23);
      s23 = __hfma2(b3, bc_h2(q11.y), s23);
      a01_0 = __hfma2(bc_h2(wdh[(cp0 + 0) * KK + k]), t01, a01_0);
      a23_0 = __hfma2(bc_h2(wdh[(cp0 + 1) * KK + k]), t23, a23_0);
      a01_1 = __hfma2(bc_h2(wdh[(cp0 + 2) * KK + k]), s01, a01_1);
      a23_1 = __hfma2(bc_h2(wdh[(cp0 + 3) * KK + k]), s23, a23_1);
    }
    size_t obase = ((size_t)b * 96 + cp0) * HW + (size_t)h * W + w;
    dwp[obase] = h2_bits(a01_0);
    dwp[obase + HW] = h2_bits(a23_0);
    dwp[obase + 2 * HW] = h2_bits(a01_1);
    dwp[obase + 3 * HW] = h2_bits(a23_1);
  }

  // cold fixup: any tap outside the staged window -> exact recompute (global)
  if (__builtin_expect(okmask != 0x1FF, 0)) {
#pragma unroll 1
    for (int q = 0; q < 6; ++q) {
      int cq = c0 + q * 4;
      int cp0 = cq >> 1;
      const float* xq = xq0 + (size_t)(q * 4) * HW;
      float a0 = 0.f, a1 = 0.f, a2 = 0.f, a3 = 0.f;
#pragma unroll 1
      for (int k = 0; k < KK; ++k) {
        int ki = k / 3, kj = k % 3;
        float oy = ob[(size_t)(2 * k) * HW];
        float ox = ob[(size_t)(2 * k + 1) * HW];
        float py = (float)(h - 1 + ki) + oy;
        float px = (float)(w - 1 + kj) + ox;
        float y0f = floorf(py), x0f = floorf(px);
        float dy = py - y0f, dx = px - x0f;
        int y0 = (int)y0f, x0 = (int)x0f;
        int y1 = y0 + 1, x1 = x0 + 1;
        float vy0 = (y0 >= 0 && y0 < H) ? 1.f : 0.f;
        float vy1 = (y1 >= 0 && y1 < H) ? 1.f : 0.f;
        float vx0 = (x0 >= 0 && x0 < W) ? 1.f : 0.f;
        float vx1 = (x1 >= 0 && x1 < W) ? 1.f : 0.f;
        int y0c = min(max(y0, 0), H - 1);
        int y1c = min(max(y1, 0), H - 1);
        int xc0 = min(max(x0, 0), W - 1);
        int xc1 = min(max(x1, 0), W - 1);
        float w0 = (1.f - dy) * (1.f - dx) * vy0 * vx0;
        float w1 = (1.f - dy) * dx * vy0 * vx1;
        float w2 = dy * (1.f - dx) * vy1 * vx0;
        float w3 = dy * dx * vy1 * vx1;
        int a00 = y0c * W + xc0, a01 = y0c * W + xc1;
        int a10 = y1c * W + xc0, a11 = y1c * W + xc1;
        __half2 wd01 = bc_h2(wdh[cp0 * KK + k]);
        __half2 wd23 = bc_h2(wdh[(cp0 + 1) * KK + k]);
        const float* p0 = xq;
        const float* p1 = xq + HW;
        const float* p2 = xq + 2 * HW;
        const float* p3 = xq + 3 * HW;
        float t0 = fmaf(w3, p0[a11], fmaf(w2, p0[a10], fmaf(w1, p0[a01], w0 * p0[a00])));
        float t1 = fmaf(w3, p1[a11], fmaf(w2, p1[a10], fmaf(w1, p1[a01], w0 * p1[a00])));
        float t2 = fmaf(w3, p2[a11], fmaf(w2, p2[a10], fmaf(w1, p2[a01], w0 * p2[a00])));
        float t3 = fmaf(w3, p3[a11], fmaf(w2, p3[a10], fmaf(w1, p3[a01], w0 * p3[a00])));
        a0 = fmaf(__low2float(wd01), t0, a0);
        a1 = fmaf(__high2float(wd01), t1, a1);
        a2 = fmaf(__low2float(wd23), t2, a2);
        a3 = fmaf(__high2float(wd23), t3, a3);
      }
      size_t obase = ((size_t)b * 96 + cp0) * HW + (size_t)h * W + w;
      dwp[obase] = h2_bits(__floats2half2_rn(a0, a1));
      dwp[obase + HW] = h2_bits(__floats2half2_rn(a2, a3));
    }
  }
}

// ---------------------------------------------------------------------------
// Kernel C: pointwise 1x1 conv via f16 MFMA  [unchanged — at memory roofline]
// ---------------------------------------------------------------------------
__global__ __launch_bounds__(256) void pointwise_mfma(
    const unsigned* __restrict__ dwp, const unsigned* __restrict__ wPW,
    float* __restrict__ out) {
  int blk = blockIdx.x;
  int nt = blk & 63;
  int mt = (blk >> 6) % 3;
  int b = blk / 192;
  int n0 = nt * 64;
  int m0 = mt * 128;
  int tid = threadIdx.x;
  int lane = tid & 63;
  int wv = tid >> 6;
  int wm = wv >> 1;
  int wn = wv & 1;
  int lpx = lane & 15;
  int lkg = lane >> 4;

  __shared__ __align__(16) unsigned sA[128 * 22];
  __shared__ __align__(16) unsigned sB[64 * 22];

  f32x4 acc[4][2];
#pragma unroll
  for (int mf = 0; mf < 4; ++mf)
#pragma unroll
    for (int nf = 0; nf < 2; ++nf) acc[mf][nf] = (f32x4){0.f, 0.f, 0.f, 0.f};

  const unsigned* dwb = dwp + (size_t)b * 96 * HW + n0;

  for (int chunk = 0; chunk < 6; ++chunk) {
    int kp0 = chunk * 16;
    __syncthreads();
#pragma unroll
    for (int t = 0; t < 8; ++t) {
      int i = t * 256 + tid;
      int m = i >> 4;
      int cd = i & 15;
      sA[m * 22 + cd] = wPW[(size_t)(m0 + m) * 96 + kp0 + cd];
    }
#pragma unroll
    for (int t = 0; t < 4; ++t) {
      int i = t * 256 + tid;
      int kp = i >> 6;
      int px = i & 63;
      sB[px * 22 + kp] = dwb[(size_t)(kp0 + kp) * HW + px];
    }
    __syncthreads();

    half8 af[4];
#pragma unroll
    for (int mf = 0; mf < 4; ++mf) {
      int m = wm * 64 + mf * 16 + lpx;
      af[mf] = ld_frag8h(&sA[m * 22 + lkg * 4]);
    }
    half8 bf[2];
#pragma unroll
    for (int nf = 0; nf < 2; ++nf) {
      int px = wn * 32 + nf * 16 + lpx;
      bf[nf] = ld_frag8h(&sB[px * 22 + lkg * 4]);
    }
#pragma unroll
    for (int mf = 0; mf < 4; ++mf)
#pragma unroll
      for (int nf = 0; nf < 2; ++nf)
        acc[mf][nf] = __builtin_amdgcn_mfma_f32_16x16x32_f16(
            af[mf], bf[nf], acc[mf][nf], 0, 0, 0);
  }

#pragma unroll
  for (int mf = 0; mf < 4; ++mf) {
#pragma unroll
    for (int nf = 0; nf < 2; ++nf) {
      int px = n0 + wn * 32 + nf * 16 + lpx;
#pragma unroll
      for (int j = 0; j < 4; ++j) {
        int o = m0 + wm * 64 + mf * 16 + lkg * 4 + j;
        out[((size_t)b * COUT + o) * HW + px] = acc[mf][nf][j];
      }
    }
  }
}

// ---------------------------------------------------------------------------
extern "C" void kernel_launch(void* const* d_in, const int* in_sizes, int n_in,
                              void* d_out, int out_size, void* d_ws,
                              size_t ws_size, hipStream_t stream) {
  const float* x = (const float*)d_in[0];
  const float* w_off = (const float*)d_in[1];
  const float* b_off = (const float*)d_in[2];
  const float* w_dw = (const float*)d_in[3];
  const float* w_pw = (const float*)d_in[4];
  float* out = (float*)d_out;

  char* ws = (char*)d_ws;
  float* offs = (float*)ws;                       // 4.72 MB
  unsigned* dwp = (unsigned*)(ws + 4718592);      // 25.17 MB (holds partials first)
  unsigned short* wA = (unsigned short*)(ws + 4718592 + 25165824);       // 110 KB
  unsigned* wPW = (unsigned*)(ws + 4718592 + 25165824 + 110592);         // 147 KB
  unsigned* wdh = (unsigned*)(ws + 4718592 + 25165824 + 110592 + 147456);// 3.5 KB
  float* part = (float*)dwp;  // 3 x 4.72 MB partials, consumed before dwp written

  int prep_n = 9 * 32 * C + COUT * (C / 2) + (C / 2) * KK;
  prep_weights<<<(prep_n + 255) / 256, 256, 0, stream>>>(w_off, w_pw, w_dw, wA,
                                                         wPW, wdh);
  offset_mfma<<<BB * 8 * 3, 512, 0, stream>>>(x, wA, part);
  offset_reduce<<<(BB * OFFC * HW / 4 + 255) / 256, 256, 0, stream>>>(
      part, b_off, offs);
  sample_dw<<<BB * 16 * 8, 256, 0, stream>>>(x, offs, wdh, dwp);
  pointwise_mfma<<<BB * 3 * 64, 256, 0, stream>>>(dwp, wPW, out);
}